// Round 4
// baseline (232.689 us; speedup 1.0000x reference)
//
#include <hip/hip_runtime.h>

// SpikeFP32LayerNorm: LayerNorm (no affine) over rows of (8192, 4096) fp32,
// statistics + normalization in FP64 per the reference circuit:
//   mean = sum(x64)/N ; var = sum((x-mean)^2)/N ; vpe = var + 1e-6
//   y = 1/vpe ; 5x NR: y = 0.5*y*(3 - vpe*y*y) ; out = fp32((x-mean) * y)
//
// Streaming two-pass, one WAVE per row (no barriers, no LDS):
//   Pass 1: cached vec4 loads, accumulate sum and sum-of-squares in FP64
//           (var = E[x^2] - mean^2; diff vs centered sum ~1e-13 << 1e-1 tol).
//   Butterfly allreduce (s and q interleaved -> 2 independent shuffle chains),
//   wave-uniform NR rsqrt.
//   Pass 2: re-read row (L2/LLC-hot, nontemporal) -> normalize -> NT store.
// Low VGPR (row never register-resident) -> high occupancy -> memory pipe
// stays full across waves' serial reduce phases.

#define LN_BATCH 8192
#define LN_N     4096
#define LN_WPB   4                 // waves per block
#define LN_THREADS (LN_WPB * 64)
#define LN_F4PT  16                // vec4 iterations per lane: 64 elems/lane
#define LN_EPS   1e-6

typedef float vfloat4 __attribute__((ext_vector_type(4)));

__global__ __launch_bounds__(LN_THREADS)
void spike_layernorm_kernel(const float* __restrict__ x, float* __restrict__ out) {
    const int wave = threadIdx.x >> 6;
    const int lane = threadIdx.x & 63;
    const int row  = blockIdx.x * LN_WPB + wave;

    const vfloat4* __restrict__ xr =
        reinterpret_cast<const vfloat4*>(x + (size_t)row * LN_N);
    vfloat4* __restrict__ orow =
        reinterpret_cast<vfloat4*>(out + (size_t)row * LN_N);

    // ---- Pass 1: streaming FP64 sum + sum-of-squares (cached loads) ----
    double s0 = 0.0, s1 = 0.0, s2 = 0.0, s3 = 0.0;
    double q0 = 0.0, q1 = 0.0, q2 = 0.0, q3 = 0.0;
#pragma unroll
    for (int i = 0; i < LN_F4PT; i += 4) {
        vfloat4 a = xr[lane + (i + 0) * 64];
        vfloat4 b = xr[lane + (i + 1) * 64];
        vfloat4 c = xr[lane + (i + 2) * 64];
        vfloat4 d = xr[lane + (i + 3) * 64];
        double t;
        t = (double)a.x; s0 += t; q0 = fma(t, t, q0);
        t = (double)a.y; s0 += t; q0 = fma(t, t, q0);
        t = (double)a.z; s0 += t; q0 = fma(t, t, q0);
        t = (double)a.w; s0 += t; q0 = fma(t, t, q0);
        t = (double)b.x; s1 += t; q1 = fma(t, t, q1);
        t = (double)b.y; s1 += t; q1 = fma(t, t, q1);
        t = (double)b.z; s1 += t; q1 = fma(t, t, q1);
        t = (double)b.w; s1 += t; q1 = fma(t, t, q1);
        t = (double)c.x; s2 += t; q2 = fma(t, t, q2);
        t = (double)c.y; s2 += t; q2 = fma(t, t, q2);
        t = (double)c.z; s2 += t; q2 = fma(t, t, q2);
        t = (double)c.w; s2 += t; q2 = fma(t, t, q2);
        t = (double)d.x; s3 += t; q3 = fma(t, t, q3);
        t = (double)d.y; s3 += t; q3 = fma(t, t, q3);
        t = (double)d.z; s3 += t; q3 = fma(t, t, q3);
        t = (double)d.w; s3 += t; q3 = fma(t, t, q3);
    }
    double s = (s0 + s1) + (s2 + s3);
    double q = (q0 + q1) + (q2 + q3);

    // Butterfly allreduce, two interleaved independent chains.
#pragma unroll
    for (int off = 1; off < 64; off <<= 1) {
        s += __shfl_xor(s, off, 64);
        q += __shfl_xor(q, off, 64);
    }

    const double mean = s * (1.0 / LN_N);
    const double var  = fma(-mean, mean, q * (1.0 / LN_N)); // E[x^2] - mean^2
    const double vpe  = var + LN_EPS;
    double y = 1.0 / vpe;               // FP64 divide seed (uniform across lanes)
#pragma unroll
    for (int it = 0; it < 5; ++it)      // 5 Newton-Raphson iterations
        y = 0.5 * y * (3.0 - vpe * (y * y));

    // ---- Pass 2: re-read (L2/LLC-hot), normalize, NT store ----
#pragma unroll
    for (int i = 0; i < LN_F4PT; ++i) {
        vfloat4 a = __builtin_nontemporal_load(&xr[lane + i * 64]);
        vfloat4 o;
        o.x = (float)(((double)a.x - mean) * y);
        o.y = (float)(((double)a.y - mean) * y);
        o.z = (float)(((double)a.z - mean) * y);
        o.w = (float)(((double)a.w - mean) * y);
        __builtin_nontemporal_store(o, &orow[lane + i * 64]);
    }
}

extern "C" void kernel_launch(void* const* d_in, const int* in_sizes, int n_in,
                              void* d_out, int out_size, void* d_ws, size_t ws_size,
                              hipStream_t stream) {
    const float* x = (const float*)d_in[0];
    float* out = (float*)d_out;
    spike_layernorm_kernel<<<LN_BATCH / LN_WPB, LN_THREADS, 0, stream>>>(x, out);
}